// Round 7
// baseline (598.663 us; speedup 1.0000x reference)
//
#include <hip/hip_runtime.h>
#include <cstdint>
#include <cstddef>

#define NLAB 128
#define TT   512
#define BB   512
#define MB   16
#define PAD_ 0
#define BOS_ 1
#define EOS_ 2
#define LN2F  0.6931471805599453f
#define LOG2E 1.4426950408889634f

#define EF_OFF   4096                                   // bytes into d_ws
#define EF_BYTES ((size_t)BB * TT * NLAB * 2)           // 64 MiB bf16

typedef float f32x4 __attribute__((ext_vector_type(4)));
typedef short s16x8 __attribute__((ext_vector_type(8)));

#if __has_builtin(__builtin_amdgcn_exp2f)
#define EXP2F(x) __builtin_amdgcn_exp2f(x)
#else
#define EXP2F(x) exp2f(x)
#endif

#if __has_builtin(__builtin_amdgcn_sched_barrier)
#define SCHED_FENCE() __builtin_amdgcn_sched_barrier(0)
#else
#define SCHED_FENCE() asm volatile("" ::: "memory")
#endif

#define WAVE_BARRIER() do {                                                   \
    asm volatile("s_waitcnt lgkmcnt(0)" ::: "memory");                        \
    SCHED_FENCE();                                                            \
    __builtin_amdgcn_s_barrier();                                             \
    SCHED_FENCE();                                                            \
} while (0)

#define MFMA_(A,B,CV) __builtin_amdgcn_mfma_f32_16x16x32_bf16((A),(B),(CV),0,0,0)

__device__ __forceinline__ bool mask_is_i32(const unsigned char* m8) {
    return m8[1] == 0;
}
__device__ __forceinline__ bool mask_at(const unsigned char* m8, int idx, bool isi) {
    if (isi) return ((const int*)m8)[idx] != 0;
    return m8[idx] != 0;
}
__device__ __forceinline__ unsigned f2bf(float f) {
    union { float f; unsigned u; } v; v.f = f;
    return (v.u + 0x7FFFu + ((v.u >> 16) & 1u)) >> 16;
}
__device__ __forceinline__ unsigned cvtpk(float lo, float hi) {   // bf16 pair RNE
    unsigned r;
    asm("v_cvt_pk_bf16_f32 %0, %1, %2" : "=v"(r) : "v"(lo), "v"(hi));
    return r;
}

// EF bf16 layout (shared by producer+consumer):
//   idx(bx,t,q,cc,mt,r) = (((bx*TT+t)*4+q)<<9) + (cc<<5) + (mt<<2) + r
//   label = 16*mt + 4*q + r ; batch = bx*16 + cc.
// Scan lane (q,cc) reads its 32 values for step t as 64 contiguous bytes.

// ---- pre-kernel: EF = exp(feats), bf16, relabeled layout -------------------
__global__ __launch_bounds__(256) void crf_ef(const float* __restrict__ feats,
                                              unsigned short* __restrict__ ef) {
    const size_t gid = (size_t)blockIdx.x * 256 + threadIdx.x; // [0, 512*512*16)
    const int    k8  = (int)(gid & 15);
    const size_t bt  = gid >> 4;                  // b*512 + t
    const int L0 = k8 * 8;
    const float4 f0 = *(const float4*)(feats + bt * NLAB + L0);
    const float4 f1 = *(const float4*)(feats + bt * NLAB + L0 + 4);
    const int mt = L0 >> 4, q0 = (L0 >> 2) & 3;   // q0 in {0,2}; f1 -> q0+1
    const int b  = (int)(bt >> 9);
    const int bx = b >> 4, cc = b & 15;
    const int t  = (int)(bt & 511);
    const size_t base = (size_t)((size_t)(bx * TT + t) * 4) << 9;
    const unsigned a0 = cvtpk(__expf(f0.x), __expf(f0.y));
    const unsigned a1 = cvtpk(__expf(f0.z), __expf(f0.w));
    const unsigned b0 = cvtpk(__expf(f1.x), __expf(f1.y));
    const unsigned b1 = cvtpk(__expf(f1.z), __expf(f1.w));
    *(uint2*)(ef + base + ((size_t)q0       << 9) + (cc << 5) + (mt << 2)) = make_uint2(a0, a1);
    *(uint2*)(ef + base + ((size_t)(q0 + 1) << 9) + (cc << 5) + (mt << 2)) = make_uint2(b0, b1);
}

// ============================================================================
// In-wave scan: 64 threads = 1 wave per block.  Wave owns 16 batches and ALL
// 128 labels.  A is relabeled so the C->B conversion is a pure in-lane
// cvtpk pack: ZERO LDS, ZERO shuffles, ZERO barriers in the loop.
//   B k-pos (kt, 8q+jj) carries label mu = 32kt+16(jj>>2)+4q+(jj&3);
//   A[mpos=cc][kpos] = exp(tr[mu][16mt+cc]);  C row (mt,4q+r) = label 16mt+4q+r
//   => b-frag[kt] elem jj = bf16(pf[2kt+(jj>>2)][jj&3])   (same lane).
// EF (exp of feats) is preloaded bf16 via a 4-deep register ring.
// blocks [32, 32+512): gold score + length, 1 batch/block.
// ============================================================================
__global__ __launch_bounds__(64, 1) void crf_scan(
        const float* __restrict__ feats,
        const int*   __restrict__ tags,
        const unsigned char* __restrict__ m8,
        const float* __restrict__ tr,
        const unsigned short* __restrict__ ef,
        float* __restrict__ gold_out,
        float* __restrict__ logZ_out) {
    const int bx  = blockIdx.x;
    const int tid = threadIdx.x;
    const bool isi = mask_is_i32(m8);

    if (bx >= BB / MB) {
        // ---------------- gold path: one batch per block --------------------
        const int b    = bx - BB / MB;
        const int lane = tid;
        const size_t fb = (size_t)b * TT * NLAB;
        float gp = 0.f; int cnt = 0;
        for (int tt = lane; tt < TT; tt += 64) {
            const int idx = b * TT + tt;
            const bool mm = mask_at(m8, idx, isi);
            cnt += mm ? 1 : 0;
            const int tg = tags[idx];
            if (tt == 0) gp += feats[fb + tg] + tr[BOS_ * NLAB + tg];
            else if (mm) gp += feats[fb + (size_t)tt * NLAB + tg]
                             + tr[tags[idx - 1] * NLAB + tg];
        }
        #pragma unroll
        for (int off = 32; off > 0; off >>= 1) {
            gp  += __shfl_xor(gp,  off, 64);
            cnt += __shfl_xor(cnt, off, 64);
        }
        if (lane == 0)
            gold_out[b] = gp + tr[tags[b * TT + cnt - 1] * NLAB + EOS_];
        return;
    }

    // ---------------- forward scan (one wave) --------------------------------
    const int q  = tid >> 4;      // quad
    const int cc = tid & 15;      // batch column
    const int G  = bx * MB + cc;
    const size_t fbase = (size_t)G * TT * NLAB;

    // ---- lengths: lane (q,cc) counts quarter q of batch cc's mask row ------
    int cnt = 0;
    if (isi) {
        const uint4* mp = (const uint4*)((const int*)m8 + (size_t)G * TT + q * 128);
        #pragma unroll 8
        for (int i = 0; i < 32; ++i) {
            uint4 v = mp[i];
            cnt += (v.x != 0) + (v.y != 0) + (v.z != 0) + (v.w != 0);
        }
    } else {
        const uint4* mp = (const uint4*)(m8 + (size_t)G * TT + q * 128);
        #pragma unroll
        for (int i = 0; i < 8; ++i) {
            uint4 v = mp[i];
            cnt += (int)((((v.x & 0x01010101u) * 0x01010101u) >> 24)
                       + (((v.y & 0x01010101u) * 0x01010101u) >> 24)
                       + (((v.z & 0x01010101u) * 0x01010101u) >> 24)
                       + (((v.w & 0x01010101u) * 0x01010101u) >> 24));
        }
    }
    cnt += __shfl_xor(cnt, 16, 64);
    cnt += __shfl_xor(cnt, 32, 64);
    const int mylen = cnt;
    int maxlen = mylen;
    maxlen = max(maxlen, __shfl_xor(maxlen, 1, 64));
    maxlen = max(maxlen, __shfl_xor(maxlen, 2, 64));
    maxlen = max(maxlen, __shfl_xor(maxlen, 4, 64));
    maxlen = max(maxlen, __shfl_xor(maxlen, 8, 64));

    // ---- loop-invariant relabeled A: 128 VGPRs -----------------------------
    // Af[mt][kt][jj] = bf16(exp(tr[mu][16mt+cc])), mu = 32kt+16(jj>>2)+4q+(jj&3)
    s16x8 Af[8][4];
    #pragma unroll
    for (int kt = 0; kt < 4; ++kt)
        #pragma unroll
        for (int jj = 0; jj < 8; ++jj) {
            const int mu = kt * 32 + (jj >> 2) * 16 + q * 4 + (jj & 3);
            const float* tp = tr + mu * NLAB + cc;
            #pragma unroll
            for (int mt = 0; mt < 8; ++mt)
                Af[mt][kt][jj] = (short)f2bf(__expf(tp[mt * 16]));
        }

    // ---- t=0 init ----------------------------------------------------------
    float pf[8][4];               // pf[mt][r] = p[label 16mt+4q+r][batch cc]
    float C;
    {
        const float n0 = tr[BOS_ * NLAB + 3] + feats[fbase + 3];
        C = n0;
        #pragma unroll
        for (int mt = 0; mt < 8; ++mt) {
            const float4 tb = *(const float4*)(tr + BOS_ * NLAB + mt * 16 + q * 4);
            const float4 ff = *(const float4*)(feats + fbase + mt * 16 + q * 4);
            pf[mt][0] = __expf(tb.x + ff.x - n0);
            pf[mt][1] = __expf(tb.y + ff.y - n0);
            pf[mt][2] = __expf(tb.z + ff.z - n0);
            pf[mt][3] = __expf(tb.w + ff.w - n0);
        }
    }

    // ---- b-frags: pure in-lane pack of pf ----------------------------------
    union BF { uint4 u; s16x8 v; };
    BF bf0, bf1, bf2, bf3;
#define PACK_B() {                                                            \
    bf0.u = make_uint4(cvtpk(pf[0][0], pf[0][1]), cvtpk(pf[0][2], pf[0][3]),  \
                       cvtpk(pf[1][0], pf[1][1]), cvtpk(pf[1][2], pf[1][3])); \
    bf1.u = make_uint4(cvtpk(pf[2][0], pf[2][1]), cvtpk(pf[2][2], pf[2][3]),  \
                       cvtpk(pf[3][0], pf[3][1]), cvtpk(pf[3][2], pf[3][3])); \
    bf2.u = make_uint4(cvtpk(pf[4][0], pf[4][1]), cvtpk(pf[4][2], pf[4][3]),  \
                       cvtpk(pf[5][0], pf[5][1]), cvtpk(pf[5][2], pf[5][3])); \
    bf3.u = make_uint4(cvtpk(pf[6][0], pf[6][1]), cvtpk(pf[6][2], pf[6][3]),  \
                       cvtpk(pf[7][0], pf[7][1]), cvtpk(pf[7][2], pf[7][3])); \
}
    PACK_B();

    // ---- EF ring: 4-deep, lane reads 64B/step ------------------------------
    const unsigned short* efp = ef + (((size_t)(bx * TT) * 4 + q) << 9) + (cc << 5);
    uint4 S00, S01, S02, S03, S10, S11, S12, S13,
          S20, S21, S22, S23, S30, S31, S32, S33;
#define LDEF(T_, A0, A1, A2, A3) {                                            \
    const uint4* p_ = (const uint4*)(efp + ((size_t)(T_) << 11));             \
    A0 = p_[0]; A1 = p_[1]; A2 = p_[2]; A3 = p_[3]; }
    LDEF(1, S00, S01, S02, S03)
    LDEF(2, S10, S11, S12, S13)
    LDEF(3, S20, S21, S22, S23)
    LDEF(4, S30, S31, S32, S33)

    int e_bc = 0;                 // lagged per-batch pow2 scale
    const f32x4 zac = {0.f, 0.f, 0.f, 0.f};

#define CMP_(V,J) ((J)==0?(V).x:(J)==1?(V).y:(J)==2?(V).z:(V).w)
#define PKC(P, E0,E1,E2,E3) ((P)<4 ? CMP_(E0,(P)&3) : (P)<8 ? CMP_(E1,(P)&3) \
                           : (P)<12 ? CMP_(E2,(P)&3) : CMP_(E3,(P)&3))

    // One step: consume EF slot, reload it for T+4; MFMA from in-reg b-frags;
    // finish = unpack-shift * sc * acc; repack.  NO LDS / barriers anywhere.
#define STEP(T_, A0, A1, A2, A3) {                                            \
    const uint4 e0_ = A0, e1_ = A1, e2_ = A2, e3_ = A3;                       \
    LDEF(min((T_) + 4, TT - 1), A0, A1, A2, A3)                               \
    SCHED_FENCE();                                                            \
    const float sc = __uint_as_float((unsigned)(127 - e_bc) << 23); /* 2^-e */\
    const bool live = (T_) < mylen;                                           \
    _Pragma("unroll")                                                         \
    for (int mt = 0; mt < 8; ++mt) {                                          \
        f32x4 x = MFMA_(Af[mt][0], bf0.v, zac); x = MFMA_(Af[mt][1], bf1.v, x); \
        f32x4 y = MFMA_(Af[mt][2], bf2.v, zac); y = MFMA_(Af[mt][3], bf3.v, y); \
        const f32x4 acc = x + y;                                              \
        _Pragma("unroll")                                                     \
        for (int h = 0; h < 2; ++h) {                                         \
            const unsigned pk = PKC(mt * 2 + h, e0_, e1_, e2_, e3_);          \
            const float fe0 = __uint_as_float(pk << 16);                      \
            const float fe1 = __uint_as_float(pk & 0xffff0000u);              \
            const float q0 = acc[2 * h]     * fe0 * sc;                       \
            const float q1 = acc[2 * h + 1] * fe1 * sc;                       \
            if (live) { pf[mt][2 * h] = q0; pf[mt][2 * h + 1] = q1; }         \
        }                                                                     \
    }                                                                         \
    if (live) C += (float)e_bc * LN2F;                                        \
    PACK_B();                                                                 \
    const int el = (int)((__float_as_uint(pf[0][3]) >> 23) & 255u) - 126;     \
    e_bc = __shfl(el, cc, 64);    /* label-3 exponent from lane (q=0,cc) */   \
}

    #pragma unroll 1
    for (int t0 = 1; t0 < maxlen; t0 += 4) {
        const int nstep = maxlen - t0;
        STEP(t0, S00, S01, S02, S03)
        if (nstep > 1) STEP(t0 + 1, S10, S11, S12, S13)
        if (nstep > 2) STEP(t0 + 2, S20, S21, S22, S23)
        if (nstep > 3) STEP(t0 + 3, S30, S31, S32, S33)
    }
#undef STEP
#undef LDEF

    // ---- logZ_b = C + log(sum_j p[j][b] * exp(tr[j,EOS])) ------------------
    float s = 0.f;
    #pragma unroll
    for (int mt = 0; mt < 8; ++mt)
        #pragma unroll
        for (int r = 0; r < 4; ++r)
            s += pf[mt][r] * __expf(tr[(mt * 16 + 4 * q + r) * NLAB + EOS_]);
    s += __shfl_xor(s, 16, 64);
    s += __shfl_xor(s, 32, 64);
    if (tid < 16) logZ_out[bx * MB + tid] = C + __logf(s);
}

// ============================================================================
// Fallback (ws too small): round-6 kernel, proven 287 us forward / absmax 0.
// ============================================================================
__global__ __launch_bounds__(256, 1) void crf_fused_fb(
        const float* __restrict__ feats,
        const int*   __restrict__ tags,
        const unsigned char* __restrict__ m8,
        const float* __restrict__ tr,
        float* __restrict__ gold_out,
        float* __restrict__ logZ_out) {
    const int bx  = blockIdx.x;
    const int tid = threadIdx.x;
    const bool isi = mask_is_i32(m8);

    if (bx >= BB / MB) {
        const int b    = (bx - BB / MB) * 4 + (tid >> 6);
        const int lane = tid & 63;
        const size_t fb = (size_t)b * TT * NLAB;
        float gp = 0.f; int cnt = 0;
        for (int tt = lane; tt < TT; tt += 64) {
            const int idx = b * TT + tt;
            const bool mm = mask_at(m8, idx, isi);
            cnt += mm ? 1 : 0;
            const int tg = tags[idx];
            if (tt == 0) gp += feats[fb + tg] + tr[BOS_ * NLAB + tg];
            else if (mm) gp += feats[fb + (size_t)tt * NLAB + tg]
                             + tr[tags[idx - 1] * NLAB + tg];
        }
        #pragma unroll
        for (int off = 32; off > 0; off >>= 1) {
            gp  += __shfl_xor(gp,  off, 64);
            cnt += __shfl_xor(cnt, off, 64);
        }
        if (lane == 0)
            gold_out[b] = gp + tr[tags[b * TT + cnt - 1] * NLAB + EOS_];
        return;
    }

    const int w = tid >> 6;
    const int l = tid & 63;
    const int a = l >> 4;
    const int c = l & 15;
    const int G = bx * MB + c;
    const size_t fbase = (size_t)G * TT * NLAB;

    __shared__ __align__(16) unsigned short P16[2][2048];
    __shared__ float red_s[4][MB];

    const int s0 = 4 * w + a, s1 = 4 * w + 16 + a;

    f32x4 F0a, F0b, F1a, F1b, F2a, F2b, F3a, F3b,
          F4a, F4b, F5a, F5b, F6a, F6b, F7a, F7b;
    {
        const f32x4* fp = (const f32x4*)(feats + fbase);
        F0a = fp[1 * 32 + s0]; F0b = fp[1 * 32 + s1];
        F1a = fp[2 * 32 + s0]; F1b = fp[2 * 32 + s1];
        F2a = fp[3 * 32 + s0]; F2b = fp[3 * 32 + s1];
        F3a = fp[4 * 32 + s0]; F3b = fp[4 * 32 + s1];
        F4a = fp[5 * 32 + s0]; F4b = fp[5 * 32 + s1];
        F5a = fp[6 * 32 + s0]; F5b = fp[6 * 32 + s1];
        F6a = fp[7 * 32 + s0]; F6b = fp[7 * 32 + s1];
        F7a = fp[8 * 32 + s0]; F7b = fp[8 * 32 + s1];
    }

    int cnt = 0;
    if (isi) {
        const uint4* mp = (const uint4*)((const int*)m8 + (size_t)G * TT + a * 128);
        #pragma unroll 8
        for (int i = 0; i < 32; ++i) {
            uint4 v = mp[i];
            cnt += (v.x != 0) + (v.y != 0) + (v.z != 0) + (v.w != 0);
        }
    } else {
        const uint4* mp = (const uint4*)(m8 + (size_t)G * TT + a * 128);
        #pragma unroll
        for (int i = 0; i < 8; ++i) {
            uint4 v = mp[i];
            cnt += (int)((((v.x & 0x01010101u) * 0x01010101u) >> 24)
                       + (((v.y & 0x01010101u) * 0x01010101u) >> 24)
                       + (((v.z & 0x01010101u) * 0x01010101u) >> 24)
                       + (((v.w & 0x01010101u) * 0x01010101u) >> 24));
        }
    }
    cnt += __shfl_xor(cnt, 16, 64);
    cnt += __shfl_xor(cnt, 32, 64);
    const int mylen = cnt;
    int maxlen = mylen;
    maxlen = max(maxlen, __shfl_xor(maxlen, 1, 64));
    maxlen = max(maxlen, __shfl_xor(maxlen, 2, 64));
    maxlen = max(maxlen, __shfl_xor(maxlen, 4, 64));
    maxlen = max(maxlen, __shfl_xor(maxlen, 8, 64));
    const int mx = maxlen - 1;

    s16x8 Af00, Af01, Af02, Af03, Af10, Af11, Af12, Af13;
    {
        s16x8* A0[4] = {&Af00, &Af01, &Af02, &Af03};
        s16x8* A1[4] = {&Af10, &Af11, &Af12, &Af13};
        #pragma unroll
        for (int kt = 0; kt < 4; ++kt)
            #pragma unroll
            for (int jj = 0; jj < 8; ++jj) {
                const float* tp = tr + (kt * 32 + a * 8 + jj) * NLAB + c;
                (*A0[kt])[jj] = (short)f2bf(__expf(tp[w * 16]));
                (*A1[kt])[jj] = (short)f2bf(__expf(tp[(w + 4) * 16]));
            }
    }

    f32x4 pf0, pf1;
    float C;
    {
        const float n0 = tr[BOS_ * NLAB + 3] + feats[fbase + 3];
        C = n0;
        const f32x4 tb0 = *(const f32x4*)(tr + BOS_ * NLAB + w * 16 + a * 4);
        const f32x4 ff0 = *(const f32x4*)(feats + fbase + w * 16 + a * 4);
        const f32x4 tb1 = *(const f32x4*)(tr + BOS_ * NLAB + (w + 4) * 16 + a * 4);
        const f32x4 ff1 = *(const f32x4*)(feats + fbase + (w + 4) * 16 + a * 4);
        #pragma unroll
        for (int r = 0; r < 4; ++r) {
            pf0[r] = __expf(tb0[r] + ff0[r] - n0);
            pf1[r] = __expf(tb1[r] + ff1[r] - n0);
        }
    }

    const int wb0 = ((2 * w       + (a >> 1)) * 16 + c) * 8 + (a & 1) * 4;
    const int wb1 = ((2 * (w + 4) + (a >> 1)) * 16 + c) * 8 + (a & 1) * 4;
    *(uint2*)&P16[0][wb0] = make_uint2(cvtpk(pf0[0], pf0[1]), cvtpk(pf0[2], pf0[3]));
    *(uint2*)&P16[0][wb1] = make_uint2(cvtpk(pf1[0], pf1[1]), cvtpk(pf1[2], pf1[3]));
    __syncthreads();

    const int rab = a * 16 + c;
    const f32x4 zac = {0.f, 0.f, 0.f, 0.f};

#define STEPF(T_, Fa, Fb) {                                                   \
    const int PB = (T_) & 1;                                                  \
    const s16x8* PR = (const s16x8*)P16[1 - PB];                              \
    const s16x8 b0 = PR[rab],       b1 = PR[64 + rab],                        \
                b2 = PR[128 + rab], b3 = PR[192 + rab];                       \
    const int p3 = (int)P16[1 - PB][c * 8 + 3];                               \
    const int e = ((p3 >> 7) & 255) - 126;                                    \
    f32x4 x0 = MFMA_(Af00, b0, zac); x0 = MFMA_(Af01, b1, x0);                \
    f32x4 y0 = MFMA_(Af02, b2, zac); y0 = MFMA_(Af03, b3, y0);                \
    f32x4 x1 = MFMA_(Af10, b0, zac); x1 = MFMA_(Af11, b1, x1);                \
    f32x4 y1 = MFMA_(Af12, b2, zac); y1 = MFMA_(Af13, b3, y1);                \
    const float sc = __uint_as_float((unsigned)(127 - e) << 23);              \
    const f32x4 acc0 = x0 + y0, acc1 = x1 + y1;                               \
    const bool live = (T_) < mylen;                                           \
    _Pragma("unroll")                                                         \
    for (int r = 0; r < 4; ++r) {                                             \
        const float q0 = acc0[r] * (EXP2F(Fa[r] * LOG2E) * sc);               \
        const float q1 = acc1[r] * (EXP2F(Fb[r] * LOG2E) * sc);               \
        if (live) { pf0[r] = q0; pf1[r] = q1; }                               \
    }                                                                         \
    if (live) C += (float)e * LN2F;                                           \
    *(uint2*)&P16[PB][wb0] = make_uint2(cvtpk(pf0[0], pf0[1]),                \
                                        cvtpk(pf0[2], pf0[3]));               \
    *(uint2*)&P16[PB][wb1] = make_uint2(cvtpk(pf1[0], pf1[1]),                \
                                        cvtpk(pf1[2], pf1[3]));               \
    WAVE_BARRIER();                                                           \
}

    #pragma unroll 1
    for (int t0 = 1; t0 < maxlen; t0 += 8) {
        const int nstep = maxlen - t0;
        STEPF(t0, F0a, F0b)
        if (nstep > 1) STEPF(t0 + 1, F1a, F1b)
        if (nstep > 2) STEPF(t0 + 2, F2a, F2b)
        if (nstep > 3) STEPF(t0 + 3, F3a, F3b)
        if (nstep > 4) STEPF(t0 + 4, F4a, F4b)
        if (nstep > 5) STEPF(t0 + 5, F5a, F5b)
        if (nstep > 6) STEPF(t0 + 6, F6a, F6b)
        if (nstep > 7) STEPF(t0 + 7, F7a, F7b)
        if (t0 + 8 < maxlen) {
            const f32x4* fp;
#define RF(i, Xa, Xb)                                                         \
            fp = (const f32x4*)(feats + fbase                                 \
                     + (size_t)min(t0 + 8 + (i), mx) * NLAB);                 \
            Xa = fp[s0]; Xb = fp[s1];
            RF(0, F0a, F0b) RF(1, F1a, F1b) RF(2, F2a, F2b) RF(3, F3a, F3b)
            RF(4, F4a, F4b) RF(5, F5a, F5b) RF(6, F6a, F6b) RF(7, F7a, F7b)
#undef RF
        }
    }
#undef STEPF

    float s = 0.f;
    #pragma unroll
    for (int r = 0; r < 4; ++r) {
        s += pf0[r] * __expf(tr[(w * 16 + 4 * a + r) * NLAB + EOS_]);
        s += pf1[r] * __expf(tr[((w + 4) * 16 + 4 * a + r) * NLAB + EOS_]);
    }
    s += __shfl_xor(s, 16, 64);
    s += __shfl_xor(s, 32, 64);
    if (l < 16) red_s[w][c] = s;
    __syncthreads();
    if (tid < 16) {
        float S = red_s[0][tid] + red_s[1][tid] + red_s[2][tid] + red_s[3][tid];
        logZ_out[bx * MB + tid] = C + __logf(S);
    }
}

// ---- final reduction: out = mean(logZ - gold) ------------------------------
__global__ void crf_finalize(const float* __restrict__ gold,
                             const float* __restrict__ logZ,
                             float* __restrict__ out) {
    __shared__ float sh[4];
    const int i = threadIdx.x;  // 256 threads
    float v = (logZ[i] - gold[i]) + (logZ[i + 256] - gold[i + 256]);
    #pragma unroll
    for (int off = 32; off > 0; off >>= 1)
        v += __shfl_xor(v, off, 64);
    if ((i & 63) == 0) sh[i >> 6] = v;
    __syncthreads();
    if (i == 0) out[0] = (sh[0] + sh[1] + sh[2] + sh[3]) * (1.0f / (float)BB);
}

extern "C" void kernel_launch(void* const* d_in, const int* in_sizes, int n_in,
                              void* d_out, int out_size, void* d_ws, size_t ws_size,
                              hipStream_t stream) {
    const float*         feats = (const float*)d_in[0];
    const int*           tags  = (const int*)d_in[1];
    const unsigned char* m8    = (const unsigned char*)d_in[2];
    const float*         tr    = (const float*)d_in[3];

    float* gold = (float*)d_ws;       // 512 floats
    float* logZ = gold + BB;          // 512 floats
    float* out  = (float*)d_out;

    if (ws_size >= EF_OFF + EF_BYTES) {
        unsigned short* ef = (unsigned short*)((char*)d_ws + EF_OFF);
        hipLaunchKernelGGL(crf_ef, dim3((BB * TT * MB) / 256), dim3(256), 0,
                           stream, feats, ef);
        hipLaunchKernelGGL(crf_scan, dim3(BB / MB + BB), dim3(64), 0, stream,
                           feats, tags, m8, tr, ef, gold, logZ);
    } else {
        hipLaunchKernelGGL(crf_fused_fb, dim3(BB / MB + BB / 4), dim3(256), 0,
                           stream, feats, tags, m8, tr, gold, logZ);
    }
    hipLaunchKernelGGL(crf_finalize, dim3(1), dim3(256), 0, stream,
                       gold, logZ, out);
}